// Round 1
// 97.738 us; speedup vs baseline: 1.0199x; 1.0199x over previous
//
#include <hip/hip_runtime.h>

#define NC 4
#define CS 512
#define NS 256
#define HD 512
#define H  256
#define GAMMA_F 12.0f
#define PHASE_SCALE 62.83185307179586477f   // pi / 0.05

#define KT 32                 // k-elements staged per round
#define NR (H / KT)           // 8 rounds

// Round 6: fuse everything into ONE kernel, drop d_ws entirely.
// Rationale (rocprof): the timed iteration was dominated by two 40.5us
// 256MiB fillBufferAligned dispatches re-poisoning the workspace; our
// compute was only ~19us. Full-K reduction per block removes the split-K
// partials, the reduce kernel, and the workspace dependency.
// grid: 4 chunks * 16 hTiles(32) * 8 tTiles(32) = 512 blocks, 256 threads
__global__ __launch_bounds__(256, 2) void rotate_score(
    const float* __restrict__ heads,     // 2048 x 512
    const float* __restrict__ relations, // 2048 x 256
    const float* __restrict__ tails,     // 1024 x 512
    float* __restrict__ out)             // 4 x 512 x 256
{
    __shared__ float2 sh[32][KT + 1];   // rotated head (re,im), +1 pad
    __shared__ float2 st[32][KT + 1];   // tail (re,im), +1 pad

    const int bid = blockIdx.x;
    const int c   = bid >> 7;          // chunk 0..3
    const int rem = bid & 127;
    const int hT  = rem >> 3;          // head tile 0..15 (32 rows)
    const int tT  = rem & 7;           // tail tile 0..7  (32 rows)

    const int hBase = c * CS + hT * 32;
    const int tBase = c * NS + tT * 32;

    const int tid = threadIdx.x;
    const int tx  = tid & 15;          // tail micro index
    const int ty  = tid >> 4;          // head micro index

    // staging: 32 rows x 8 lanes x 4 k-elems (float4)
    const int srow = tid >> 3;         // 0..31
    const int sk   = (tid & 7) * 4;    // 0,4,...,28

    const float* hp0 = heads     + (size_t)(hBase + srow) * HD + sk;
    const float* rp0 = relations + (size_t)(hBase + srow) * H  + sk;
    const float* tp0 = tails     + (size_t)(tBase + srow) * HD + sk;

    // prefetch round 0
    float4 hre = *reinterpret_cast<const float4*>(hp0);
    float4 him = *reinterpret_cast<const float4*>(hp0 + H);
    float4 rel = *reinterpret_cast<const float4*>(rp0);
    float4 tre = *reinterpret_cast<const float4*>(tp0);
    float4 tim = *reinterpret_cast<const float4*>(tp0 + H);

    float acc00 = 0.f, acc01 = 0.f, acc10 = 0.f, acc11 = 0.f;

    for (int r = 0; r < NR; ++r) {
        if (r) __syncthreads();        // previous round's LDS reads complete

        // ---- rotate heads inline, stage interleaved (re,im) ----
        {
            float s, cc;
            __sincosf(rel.x * PHASE_SCALE, &s, &cc);
            sh[srow][sk + 0] = make_float2(hre.x * cc - him.x * s,
                                           hre.x * s + him.x * cc);
            __sincosf(rel.y * PHASE_SCALE, &s, &cc);
            sh[srow][sk + 1] = make_float2(hre.y * cc - him.y * s,
                                           hre.y * s + him.y * cc);
            __sincosf(rel.z * PHASE_SCALE, &s, &cc);
            sh[srow][sk + 2] = make_float2(hre.z * cc - him.z * s,
                                           hre.z * s + him.z * cc);
            __sincosf(rel.w * PHASE_SCALE, &s, &cc);
            sh[srow][sk + 3] = make_float2(hre.w * cc - him.w * s,
                                           hre.w * s + him.w * cc);
        }
        st[srow][sk + 0] = make_float2(tre.x, tim.x);
        st[srow][sk + 1] = make_float2(tre.y, tim.y);
        st[srow][sk + 2] = make_float2(tre.z, tim.z);
        st[srow][sk + 3] = make_float2(tre.w, tim.w);

        __syncthreads();               // staging visible

        // ---- issue next round's global loads; latency hides under compute
        if (r + 1 < NR) {
            const int kOff = (r + 1) * KT;
            hre = *reinterpret_cast<const float4*>(hp0 + kOff);
            him = *reinterpret_cast<const float4*>(hp0 + H + kOff);
            rel = *reinterpret_cast<const float4*>(rp0 + kOff);
            tre = *reinterpret_cast<const float4*>(tp0 + kOff);
            tim = *reinterpret_cast<const float4*>(tp0 + H + kOff);
        }

        #pragma unroll
        for (int kk = 0; kk < KT; ++kk) {
            float2 h0 = sh[ty     ][kk];
            float2 h1 = sh[ty + 16][kk];
            float2 t0 = st[tx     ][kk];
            float2 t1 = st[tx + 16][kk];
            float dr, di;
            dr = h0.x - t0.x; di = h0.y - t0.y;
            acc00 += __builtin_amdgcn_sqrtf(fmaf(dr, dr, di * di));
            dr = h0.x - t1.x; di = h0.y - t1.y;
            acc01 += __builtin_amdgcn_sqrtf(fmaf(dr, dr, di * di));
            dr = h1.x - t0.x; di = h1.y - t0.y;
            acc10 += __builtin_amdgcn_sqrtf(fmaf(dr, dr, di * di));
            dr = h1.x - t1.x; di = h1.y - t1.y;
            acc11 += __builtin_amdgcn_sqrtf(fmaf(dr, dr, di * di));
        }
    }

    // epilogue: fused GAMMA - score, direct to out
    const size_t cbase = (size_t)c * CS * NS;
    const int i0 = hT * 32 + ty;
    const int j0 = tT * 32 + tx;
    out[cbase + (size_t)i0        * NS + j0     ] = GAMMA_F - acc00;
    out[cbase + (size_t)i0        * NS + j0 + 16] = GAMMA_F - acc01;
    out[cbase + (size_t)(i0 + 16) * NS + j0     ] = GAMMA_F - acc10;
    out[cbase + (size_t)(i0 + 16) * NS + j0 + 16] = GAMMA_F - acc11;
}

extern "C" void kernel_launch(void* const* d_in, const int* in_sizes, int n_in,
                              void* d_out, int out_size, void* d_ws, size_t ws_size,
                              hipStream_t stream) {
    (void)in_sizes; (void)n_in; (void)ws_size; (void)out_size; (void)d_ws;
    const float* heads = (const float*)d_in[0];
    const float* rels  = (const float*)d_in[1];
    const float* tails = (const float*)d_in[2];

    rotate_score<<<512, 256, 0, stream>>>(heads, rels, tails, (float*)d_out);
}